// Round 1
// baseline (972.417 us; speedup 1.0000x reference)
//
#include <hip/hip_runtime.h>

#define TT 36
#define KK 160
#define NPOLE 40
#define PP 4096
#define MAXIT 100

#define COLS 32
#define AST 164   // padded LDS stride for A rows (16B aligned, conflict-free)
#define YST 36    // padded LDS stride for y rows

// ws float offsets
#define WS_LINV  0
#define WS_LAMBD 1
#define WS_TTS   2      // 100 floats
#define WS_KSTAR 128    // int
#define WS_D     256    // 36*160
#define WS_A     6144   // 160*160
#define WS_PART  32768  // 100*256 per-block per-iter partial norms

__global__ void setup_kernel(const float* __restrict__ Drr,
                             const float* __restrict__ Dth,
                             float* __restrict__ ws) {
  __shared__ float Dl[TT * KK];
  __shared__ float Gl[KK];
  __shared__ double red[256];
  const int tid = threadIdx.x;

  // unnormalized dictionary: cols [pr*c, (-1)^i pr*c, pr*s, (-1)^i pr*s]
  for (int idx = tid; idx < TT * KK; idx += 256) {
    int i = idx / KK, k = idx % KK;
    int g = k / NPOLE, n = k % NPOLE;
    float rr = Drr[n], th = Dth[n];
    float pr = powf(rr, (float)i);
    float ang = (float)i * th;
    float tri = (g < 2) ? cosf(ang) : sinf(ang);
    float sgn = ((g & 1) && (i & 1)) ? -1.0f : 1.0f;
    Dl[idx] = pr * tri * sgn;
  }
  __syncthreads();
  if (tid < KK) {
    float s = 0.f;
    for (int i = 0; i < TT; i++) { float v = Dl[i * KK + tid]; s += v * v; }
    float gn = sqrtf(s);
    Gl[tid] = (gn == 0.f) ? sqrtf((float)TT) : gn;
  }
  __syncthreads();
  for (int idx = tid; idx < TT * KK; idx += 256) {
    int k = idx % KK;
    Dl[idx] = Dl[idx] / Gl[k];
  }
  __syncthreads();
  for (int idx = tid; idx < TT * KK; idx += 256) ws[WS_D + idx] = Dl[idx];

  // DtD -> ws[WS_A], accumulate Frobenius^2
  double ss = 0.0;
  for (int idx = tid; idx < KK * KK; idx += 256) {
    int a = idx / KK, b = idx % KK;
    float s = 0.f;
    for (int t = 0; t < TT; t++) s += Dl[t * KK + a] * Dl[t * KK + b];
    ws[WS_A + idx] = s;
    ss += (double)s * (double)s;
  }
  red[tid] = ss;
  __syncthreads();
  for (int off = 128; off > 0; off >>= 1) {
    if (tid < off) red[tid] += red[tid + off];
    __syncthreads();
  }
  float L = (float)sqrt(red[0]);
  float linv = 1.0f / L;
  for (int idx = tid; idx < KK * KK; idx += 256) {
    int a = idx / KK, b = idx % KK;
    float v = ws[WS_A + idx] * linv;
    ws[WS_A + idx] = ((a == b) ? 1.0f : 0.0f) - v;
  }
  if (tid == 0) {
    ws[WS_LINV] = linv;
    ws[WS_LAMBD] = 0.1f * linv;
    double ts = 1.0;
    for (int k = 0; k < MAXIT; k++) {
      double tn = (1.0 + sqrt(1.0 + 4.0 * ts * ts)) * 0.5;
      ws[WS_TTS + k] = (float)((ts - 1.0) / tn);
      ts = tn;
    }
  }
}

__device__ __forceinline__ void fma_tile(float4 acc[5], const float4 a[5],
                                         const float4& y0, const float4& y1,
                                         const float4& y2, const float4& y3) {
#pragma unroll
  for (int i = 0; i < 5; i++) {
    acc[i].x = fmaf(a[i].x, y0.x, fmaf(a[i].y, y1.x, fmaf(a[i].z, y2.x, fmaf(a[i].w, y3.x, acc[i].x))));
    acc[i].y = fmaf(a[i].x, y0.y, fmaf(a[i].y, y1.y, fmaf(a[i].z, y2.y, fmaf(a[i].w, y3.y, acc[i].y))));
    acc[i].z = fmaf(a[i].x, y0.z, fmaf(a[i].y, y1.z, fmaf(a[i].z, y2.z, fmaf(a[i].w, y3.z, acc[i].z))));
    acc[i].w = fmaf(a[i].x, y0.w, fmaf(a[i].y, y1.w, fmaf(a[i].z, y2.w, fmaf(a[i].w, y3.w, acc[i].w))));
  }
}

// mode 0: run MAXIT iters, log partial norms per iter, write x_100 to out.
// mode 1: read k*; if k* >= MAXIT-1 nothing to do; else re-run k*+1 iters and
//         overwrite out with x_{k*+1} (== reference's frozen output).
__global__ __launch_bounds__(256, 1)
void fista_kernel(const float* __restrict__ x, float* __restrict__ out,
                  float* __restrict__ ws, int mode) {
  __shared__ __align__(16) float Al[KK * AST];   // 104,960 B
  __shared__ __align__(16) float yl[164 * YST];  //  23,616 B (padded rows + prefetch overread)
  __shared__ float red4[4];

  int niter = MAXIT;
  if (mode == 1) {
    int kstar = *(const int*)&ws[WS_KSTAR];
    if (kstar >= MAXIT - 1) return;
    niter = kstar + 1;
  }

  const int tid = threadIdx.x;
  const int bid = blockIdx.x;
  const int g  = tid & 7;    // col group: cols 4g..4g+3
  const int rg = tid >> 3;   // row group: rows 5rg..5rg+4
  const int c0 = bid * COLS;
  const int bb = c0 / PP;
  const int p0 = c0 % PP;
  const float linv  = ws[WS_LINV];
  const float lambd = ws[WS_LAMBD];
  const int arow = 5 * rg;

  // ---- prologue: stage D (into Al area) + x slice (into yl area) ----
  for (int idx = tid; idx < TT * KK; idx += 256) Al[idx] = ws[WS_D + idx];
  for (int idx = tid; idx < TT * COLS; idx += 256) {
    int t = idx >> 5, c = idx & 31;
    yl[t * YST + c] = x[((size_t)bb * TT + t) * PP + p0 + c];
  }
  __syncthreads();

  // DtY (scaled by linv) lives in registers for the whole kernel
  float4 dty[5];
#pragma unroll
  for (int i = 0; i < 5; i++) dty[i] = make_float4(0.f, 0.f, 0.f, 0.f);
  for (int t = 0; t < TT; t++) {
    const float4 xv = *reinterpret_cast<const float4*>(&yl[t * YST + 4 * g]);
#pragma unroll
    for (int i = 0; i < 5; i++) {
      float d = Al[t * KK + arow + i];
      dty[i].x = fmaf(d, xv.x, dty[i].x);
      dty[i].y = fmaf(d, xv.y, dty[i].y);
      dty[i].z = fmaf(d, xv.z, dty[i].z);
      dty[i].w = fmaf(d, xv.w, dty[i].w);
    }
  }
#pragma unroll
  for (int i = 0; i < 5; i++) {
    dty[i].x *= linv; dty[i].y *= linv; dty[i].z *= linv; dty[i].w *= linv;
  }
  __syncthreads();

  // load A into padded LDS layout; zero y state
  for (int idx = tid; idx < KK * KK / 4; idx += 256) {
    int r = idx / 40, c4 = (idx % 40) * 4;
    float4 v = reinterpret_cast<const float4*>(&ws[WS_A])[idx];
    *reinterpret_cast<float4*>(&Al[r * AST + c4]) = v;
  }
  for (int idx = tid; idx < 164 * YST; idx += 256) yl[idx] = 0.f;
  float4 xo[5];
#pragma unroll
  for (int i = 0; i < 5; i++) xo[i] = make_float4(0.f, 0.f, 0.f, 0.f);
  __syncthreads();

  for (int it = 0; it < niter; it++) {
    float4 acc[5];
#pragma unroll
    for (int i = 0; i < 5; i++) acc[i] = make_float4(0.f, 0.f, 0.f, 0.f);

    float4 av0[5], av1[5];
    float4 ya0, ya1, ya2, ya3, yb0, yb1, yb2, yb3;
#pragma unroll
    for (int i = 0; i < 5; i++)
      av0[i] = *reinterpret_cast<const float4*>(&Al[(arow + i) * AST + 0]);
    ya0 = *reinterpret_cast<const float4*>(&yl[0 * YST + 4 * g]);
    ya1 = *reinterpret_cast<const float4*>(&yl[1 * YST + 4 * g]);
    ya2 = *reinterpret_cast<const float4*>(&yl[2 * YST + 4 * g]);
    ya3 = *reinterpret_cast<const float4*>(&yl[3 * YST + 4 * g]);
    for (int jb = 0; jb < KK; jb += 8) {
#pragma unroll
      for (int i = 0; i < 5; i++)
        av1[i] = *reinterpret_cast<const float4*>(&Al[(arow + i) * AST + jb + 4]);
      yb0 = *reinterpret_cast<const float4*>(&yl[(jb + 4) * YST + 4 * g]);
      yb1 = *reinterpret_cast<const float4*>(&yl[(jb + 5) * YST + 4 * g]);
      yb2 = *reinterpret_cast<const float4*>(&yl[(jb + 6) * YST + 4 * g]);
      yb3 = *reinterpret_cast<const float4*>(&yl[(jb + 7) * YST + 4 * g]);
      fma_tile(acc, av0, ya0, ya1, ya2, ya3);
#pragma unroll
      for (int i = 0; i < 5; i++)   // overreads land in row padding (jb+8==160)
        av0[i] = *reinterpret_cast<const float4*>(&Al[(arow + i) * AST + jb + 8]);
      ya0 = *reinterpret_cast<const float4*>(&yl[(jb + 8) * YST + 4 * g]);
      ya1 = *reinterpret_cast<const float4*>(&yl[(jb + 9) * YST + 4 * g]);
      ya2 = *reinterpret_cast<const float4*>(&yl[(jb + 10) * YST + 4 * g]);
      ya3 = *reinterpret_cast<const float4*>(&yl[(jb + 11) * YST + 4 * g]);
      fma_tile(acc, av1, yb0, yb1, yb2, yb3);
    }

    const float tt = ws[WS_TTS + it];
    float lsum = 0.f;
    float4 yn[5];
#pragma unroll
    for (int i = 0; i < 5; i++) {
#define EPI(C) { \
      float ov = xo[i].C; \
      float v  = acc[i].C + dty[i].C; \
      float aa = fabsf(v) - lambd; \
      float xv = (aa > 0.f) ? ((v < 0.f) ? -aa : aa) : 0.f; \
      float dd = xv - ov; \
      lsum = fmaf(dd, dd, lsum); \
      yn[i].C = fmaf(tt, dd, xv); \
      xo[i].C = xv; }
      EPI(x) EPI(y) EPI(z) EPI(w)
#undef EPI
    }

    __syncthreads();   // all yl reads of this iteration done
#pragma unroll
    for (int i = 0; i < 5; i++)
      *reinterpret_cast<float4*>(&yl[(arow + i) * YST + 4 * g]) = yn[i];

#pragma unroll
    for (int off = 32; off > 0; off >>= 1) lsum += __shfl_down(lsum, off, 64);
    if ((tid & 63) == 0) red4[tid >> 6] = lsum;
    __syncthreads();   // yl writes + red4 visible
    if (mode == 0 && tid == 0)
      ws[WS_PART + it * 256 + bid] = red4[0] + red4[1] + red4[2] + red4[3];
  }

#pragma unroll
  for (int i = 0; i < 5; i++)
    *reinterpret_cast<float4*>(&out[((size_t)bb * KK + arow + i) * PP + p0 + 4 * g]) = xo[i];
}

__global__ void conv_scan(float* __restrict__ ws) {
  __shared__ float red[256];
  const int tid = threadIdx.x;
  int kstar = MAXIT;
  for (int it = 0; it < MAXIT; it++) {
    red[tid] = ws[WS_PART + it * 256 + tid];
    __syncthreads();
    for (int off = 128; off > 0; off >>= 1) {
      if (tid < off) red[tid] += red[tid + off];
      __syncthreads();
    }
    float s = red[0];
    __syncthreads();
    float denom = (it == 0) ? 4096.0f : 160.0f;
    if (sqrtf(s) / denom < 1e-4f) { kstar = it; break; }  // uniform across block
  }
  if (tid == 0) *reinterpret_cast<int*>(&ws[WS_KSTAR]) = kstar;
}

extern "C" void kernel_launch(void* const* d_in, const int* in_sizes, int n_in,
                              void* d_out, int out_size, void* d_ws, size_t ws_size,
                              hipStream_t stream) {
  const float* Drr = (const float*)d_in[0];
  const float* Dth = (const float*)d_in[1];
  const float* x   = (const float*)d_in[2];
  float* out = (float*)d_out;
  float* ws  = (float*)d_ws;

  setup_kernel<<<1, 256, 0, stream>>>(Drr, Dth, ws);
  fista_kernel<<<256, 256, 0, stream>>>(x, out, ws, 0);
  conv_scan<<<1, 256, 0, stream>>>(ws);
  fista_kernel<<<256, 256, 0, stream>>>(x, out, ws, 1);
}

// Round 2
// 808.008 us; speedup vs baseline: 1.2035x; 1.2035x over previous
//
#include <hip/hip_runtime.h>

#define TT 36
#define KK 160
#define NPOLE 40
#define PP 4096
#define MAXIT 100

#define COLS 32
#define NTHR 512
#define AST 164   // padded LDS stride for A rows (16B aligned, conflict-free)
#define YST 36    // padded LDS stride for y rows

// ws float offsets
#define WS_LINV  0
#define WS_LAMBD 1
#define WS_TTS   2      // 100 floats
#define WS_KSTAR 128    // int
#define WS_D     256    // 36*160
#define WS_A     6144   // 160*160
#define WS_PART  32768  // 100*256 per-block per-iter partial norms

__global__ void setup_kernel(const float* __restrict__ Drr,
                             const float* __restrict__ Dth,
                             float* __restrict__ ws) {
  __shared__ float Dl[TT * KK];
  __shared__ float Gl[KK];
  __shared__ double red[1024];
  const int tid = threadIdx.x;
  const int nt = blockDim.x;

  for (int idx = tid; idx < TT * KK; idx += nt) {
    int i = idx / KK, k = idx % KK;
    int g = k / NPOLE, n = k % NPOLE;
    float rr = Drr[n], th = Dth[n];
    float pr = powf(rr, (float)i);
    float ang = (float)i * th;
    float tri = (g < 2) ? cosf(ang) : sinf(ang);
    float sgn = ((g & 1) && (i & 1)) ? -1.0f : 1.0f;
    Dl[idx] = pr * tri * sgn;
  }
  __syncthreads();
  if (tid < KK) {
    float s = 0.f;
    for (int i = 0; i < TT; i++) { float v = Dl[i * KK + tid]; s += v * v; }
    float gn = sqrtf(s);
    Gl[tid] = (gn == 0.f) ? sqrtf((float)TT) : gn;
  }
  __syncthreads();
  for (int idx = tid; idx < TT * KK; idx += nt) {
    int k = idx % KK;
    Dl[idx] = Dl[idx] / Gl[k];
  }
  __syncthreads();
  for (int idx = tid; idx < TT * KK; idx += nt) ws[WS_D + idx] = Dl[idx];

  double ss = 0.0;
  for (int idx = tid; idx < KK * KK; idx += nt) {
    int a = idx / KK, b = idx % KK;
    float s = 0.f;
    for (int t = 0; t < TT; t++) s += Dl[t * KK + a] * Dl[t * KK + b];
    ws[WS_A + idx] = s;
    ss += (double)s * (double)s;
  }
  red[tid] = ss;
  __syncthreads();
  for (int off = nt / 2; off > 0; off >>= 1) {
    if (tid < off) red[tid] += red[tid + off];
    __syncthreads();
  }
  float L = (float)sqrt(red[0]);
  float linv = 1.0f / L;
  for (int idx = tid; idx < KK * KK; idx += nt) {
    int a = idx / KK, b = idx % KK;
    float v = ws[WS_A + idx] * linv;
    ws[WS_A + idx] = ((a == b) ? 1.0f : 0.0f) - v;
  }
  if (tid == 0) {
    ws[WS_LINV] = linv;
    ws[WS_LAMBD] = 0.1f * linv;
    double ts = 1.0;
    for (int k = 0; k < MAXIT; k++) {
      double tn = (1.0 + sqrt(1.0 + 4.0 * ts * ts)) * 0.5;
      ws[WS_TTS + k] = (float)((ts - 1.0) / tn);
      ts = tn;
    }
  }
}

__device__ __forceinline__ void fma_tile2(float2 acc[5], const float4 a[5],
                                          const float2& y0, const float2& y1,
                                          const float2& y2, const float2& y3) {
#pragma unroll
  for (int i = 0; i < 5; i++) {
    acc[i].x = fmaf(a[i].x, y0.x, fmaf(a[i].y, y1.x, fmaf(a[i].z, y2.x, fmaf(a[i].w, y3.x, acc[i].x))));
    acc[i].y = fmaf(a[i].x, y0.y, fmaf(a[i].y, y1.y, fmaf(a[i].z, y2.y, fmaf(a[i].w, y3.y, acc[i].y))));
  }
}

// mode 0: run MAXIT iters, log partial norms per iter, write x_100 to out.
// mode 1: read k*; if k* >= MAXIT-1 nothing to do; else re-run k*+1 iters.
__global__ __launch_bounds__(NTHR, 2)
void fista_kernel(const float* __restrict__ x, float* __restrict__ out,
                  float* __restrict__ ws, int mode) {
  __shared__ __align__(16) float Al[KK * AST];   // 104,960 B
  __shared__ __align__(16) float yl[164 * YST];  //  23,616 B
  __shared__ float red8[8];

  int niter = MAXIT;
  if (mode == 1) {
    int kstar = *(const int*)&ws[WS_KSTAR];
    if (kstar >= MAXIT - 1) return;
    niter = kstar + 1;
  }

  const int tid = threadIdx.x;
  const int bid = blockIdx.x;
  const int g  = tid & 15;   // col pair: cols 2g, 2g+1
  const int rg = tid >> 4;   // row group: rows 5rg..5rg+4
  const int c0 = bid * COLS;
  const int bb = c0 / PP;
  const int p0 = c0 % PP;
  const float linv  = ws[WS_LINV];
  const float lambd = ws[WS_LAMBD];
  const int arow = 5 * rg;

  // ---- prologue: stage D (into Al area) + x slice (into yl area) ----
  for (int idx = tid; idx < TT * KK; idx += NTHR) Al[idx] = ws[WS_D + idx];
  for (int idx = tid; idx < TT * COLS; idx += NTHR) {
    int t = idx >> 5, c = idx & 31;
    yl[t * YST + c] = x[((size_t)bb * TT + t) * PP + p0 + c];
  }
  __syncthreads();

  // DtY (scaled by linv) lives in registers for the whole kernel
  float2 dty[5];
#pragma unroll
  for (int i = 0; i < 5; i++) dty[i] = make_float2(0.f, 0.f);
  for (int t = 0; t < TT; t++) {
    const float2 xv = *reinterpret_cast<const float2*>(&yl[t * YST + 2 * g]);
#pragma unroll
    for (int i = 0; i < 5; i++) {
      float d = Al[t * KK + arow + i];
      dty[i].x = fmaf(d, xv.x, dty[i].x);
      dty[i].y = fmaf(d, xv.y, dty[i].y);
    }
  }
#pragma unroll
  for (int i = 0; i < 5; i++) { dty[i].x *= linv; dty[i].y *= linv; }
  __syncthreads();

  // load A into padded LDS layout; zero y state
  for (int idx = tid; idx < KK * KK / 4; idx += NTHR) {
    int r = idx / 40, c4 = (idx % 40) * 4;
    float4 v = reinterpret_cast<const float4*>(&ws[WS_A])[idx];
    *reinterpret_cast<float4*>(&Al[r * AST + c4]) = v;
  }
  for (int idx = tid; idx < 164 * YST; idx += NTHR) yl[idx] = 0.f;
  float2 xo[5];
#pragma unroll
  for (int i = 0; i < 5; i++) xo[i] = make_float2(0.f, 0.f);
  __syncthreads();

  for (int it = 0; it < niter; it++) {
    float2 acc[5];
#pragma unroll
    for (int i = 0; i < 5; i++) acc[i] = make_float2(0.f, 0.f);

    float4 av0[5], av1[5];
    float2 ya0, ya1, ya2, ya3, yb0, yb1, yb2, yb3;
#pragma unroll
    for (int i = 0; i < 5; i++)
      av0[i] = *reinterpret_cast<const float4*>(&Al[(arow + i) * AST + 0]);
    ya0 = *reinterpret_cast<const float2*>(&yl[0 * YST + 2 * g]);
    ya1 = *reinterpret_cast<const float2*>(&yl[1 * YST + 2 * g]);
    ya2 = *reinterpret_cast<const float2*>(&yl[2 * YST + 2 * g]);
    ya3 = *reinterpret_cast<const float2*>(&yl[3 * YST + 2 * g]);
    for (int jb = 0; jb < KK; jb += 8) {
#pragma unroll
      for (int i = 0; i < 5; i++)
        av1[i] = *reinterpret_cast<const float4*>(&Al[(arow + i) * AST + jb + 4]);
      yb0 = *reinterpret_cast<const float2*>(&yl[(jb + 4) * YST + 2 * g]);
      yb1 = *reinterpret_cast<const float2*>(&yl[(jb + 5) * YST + 2 * g]);
      yb2 = *reinterpret_cast<const float2*>(&yl[(jb + 6) * YST + 2 * g]);
      yb3 = *reinterpret_cast<const float2*>(&yl[(jb + 7) * YST + 2 * g]);
      fma_tile2(acc, av0, ya0, ya1, ya2, ya3);
#pragma unroll
      for (int i = 0; i < 5; i++)   // overreads land in row padding (jb+8==160)
        av0[i] = *reinterpret_cast<const float4*>(&Al[(arow + i) * AST + jb + 8]);
      ya0 = *reinterpret_cast<const float2*>(&yl[(jb + 8) * YST + 2 * g]);
      ya1 = *reinterpret_cast<const float2*>(&yl[(jb + 9) * YST + 2 * g]);
      ya2 = *reinterpret_cast<const float2*>(&yl[(jb + 10) * YST + 2 * g]);
      ya3 = *reinterpret_cast<const float2*>(&yl[(jb + 11) * YST + 2 * g]);
      fma_tile2(acc, av1, yb0, yb1, yb2, yb3);
    }

    const float tt = ws[WS_TTS + it];
    float lsum = 0.f;
    float2 yn[5];
#pragma unroll
    for (int i = 0; i < 5; i++) {
#define EPI(C) { \
      float ov = xo[i].C; \
      float v  = acc[i].C + dty[i].C; \
      float aa = fabsf(v) - lambd; \
      float xv = (aa > 0.f) ? ((v < 0.f) ? -aa : aa) : 0.f; \
      float dd = xv - ov; \
      lsum = fmaf(dd, dd, lsum); \
      yn[i].C = fmaf(tt, dd, xv); \
      xo[i].C = xv; }
      EPI(x) EPI(y)
#undef EPI
    }

    __syncthreads();   // all yl reads of this iteration done
#pragma unroll
    for (int i = 0; i < 5; i++)
      *reinterpret_cast<float2*>(&yl[(arow + i) * YST + 2 * g]) = yn[i];

#pragma unroll
    for (int off = 32; off > 0; off >>= 1) lsum += __shfl_down(lsum, off, 64);
    if ((tid & 63) == 0) red8[tid >> 6] = lsum;
    __syncthreads();   // yl writes + red8 visible
    if (mode == 0 && tid == 0) {
      float s = 0.f;
#pragma unroll
      for (int w = 0; w < 8; w++) s += red8[w];
      ws[WS_PART + it * 256 + bid] = s;
    }
  }

#pragma unroll
  for (int i = 0; i < 5; i++)
    *reinterpret_cast<float2*>(&out[((size_t)bb * KK + arow + i) * PP + p0 + 2 * g]) = xo[i];
}

__global__ void conv_scan(float* __restrict__ ws) {
  __shared__ unsigned char conv[MAXIT];
  const int tid = threadIdx.x;
  if (tid < MAXIT) {
    float s = 0.f;
    for (int b = 0; b < 256; b++) s += ws[WS_PART + tid * 256 + b];
    float denom = (tid == 0) ? 4096.0f : 160.0f;
    conv[tid] = (sqrtf(s) / denom < 1e-4f) ? 1 : 0;
  }
  __syncthreads();
  if (tid == 0) {
    int kstar = MAXIT;
    for (int it = 0; it < MAXIT; it++)
      if (conv[it]) { kstar = it; break; }
    *reinterpret_cast<int*>(&ws[WS_KSTAR]) = kstar;
  }
}

extern "C" void kernel_launch(void* const* d_in, const int* in_sizes, int n_in,
                              void* d_out, int out_size, void* d_ws, size_t ws_size,
                              hipStream_t stream) {
  const float* Drr = (const float*)d_in[0];
  const float* Dth = (const float*)d_in[1];
  const float* x   = (const float*)d_in[2];
  float* out = (float*)d_out;
  float* ws  = (float*)d_ws;

  setup_kernel<<<1, 1024, 0, stream>>>(Drr, Dth, ws);
  fista_kernel<<<256, NTHR, 0, stream>>>(x, out, ws, 0);
  conv_scan<<<1, 128, 0, stream>>>(ws);
  fista_kernel<<<256, NTHR, 0, stream>>>(x, out, ws, 1);
}

// Round 3
// 405.681 us; speedup vs baseline: 2.3970x; 1.9917x over previous
//
#include <hip/hip_runtime.h>

#define TT 36
#define KK 160
#define NPOLE 40
#define PP 4096
#define MAXIT 100
#define COLS 32
#define NW 10
#define NTHR 640
#define YS 168   // bf16 stride per column (padded from 160)

// ws float offsets
#define WS_LINV  0
#define WS_LAMBD 1
#define WS_TTS   2      // 100 floats
#define WS_KSTAR 128    // int
#define WS_PART  160    // 100 floats, atomicAdd-accumulated per-iter norm^2
#define WS_D     512    // 36*160 fp32
#define WS_A     6400   // 160*160 fp32 (DtD scratch)
#define WS_AH    32000  // 160*160 bf16 hi (as shorts; 12800 floats)
#define WS_AL    44800  // 160*160 bf16 lo
// total 57600 floats = 230400 B

typedef float  floatx4 __attribute__((ext_vector_type(4)));
typedef short  shortx8 __attribute__((ext_vector_type(8)));
typedef short  shortx4 __attribute__((ext_vector_type(4)));

__device__ __forceinline__ short f2bf(float v) {
  unsigned u = __float_as_uint(v);
  unsigned r = (u + 0x7FFFu + ((u >> 16) & 1u)) >> 16;  // RNE
  return (short)r;
}
__device__ __forceinline__ float bf2f(short s) {
  return __uint_as_float(((unsigned)(unsigned short)s) << 16);
}

__global__ void setup_kernel(const float* __restrict__ Drr,
                             const float* __restrict__ Dth,
                             float* __restrict__ ws) {
  __shared__ float Dl[TT * KK];
  __shared__ float Gl[KK];
  __shared__ double red[1024];
  const int tid = threadIdx.x;
  const int nt = blockDim.x;

  for (int idx = tid; idx < MAXIT; idx += nt) ws[WS_PART + idx] = 0.f;

  for (int idx = tid; idx < TT * KK; idx += nt) {
    int i = idx / KK, k = idx % KK;
    int g = k / NPOLE, n = k % NPOLE;
    float rr = Drr[n], th = Dth[n];
    float pr = powf(rr, (float)i);
    float ang = (float)i * th;
    float tri = (g < 2) ? cosf(ang) : sinf(ang);
    float sgn = ((g & 1) && (i & 1)) ? -1.0f : 1.0f;
    Dl[idx] = pr * tri * sgn;
  }
  __syncthreads();
  if (tid < KK) {
    float s = 0.f;
    for (int i = 0; i < TT; i++) { float v = Dl[i * KK + tid]; s += v * v; }
    float gn = sqrtf(s);
    Gl[tid] = (gn == 0.f) ? sqrtf((float)TT) : gn;
  }
  __syncthreads();
  for (int idx = tid; idx < TT * KK; idx += nt) {
    int k = idx % KK;
    Dl[idx] = Dl[idx] / Gl[k];
  }
  __syncthreads();
  for (int idx = tid; idx < TT * KK; idx += nt) ws[WS_D + idx] = Dl[idx];

  double ss = 0.0;
  for (int idx = tid; idx < KK * KK; idx += nt) {
    int a = idx / KK, b = idx % KK;
    float s = 0.f;
    for (int t = 0; t < TT; t++) s += Dl[t * KK + a] * Dl[t * KK + b];
    ws[WS_A + idx] = s;
    ss += (double)s * (double)s;
  }
  red[tid] = ss;
  __syncthreads();
  for (int off = nt / 2; off > 0; off >>= 1) {
    if (tid < off) red[tid] += red[tid + off];
    __syncthreads();
  }
  float L = (float)sqrt(red[0]);
  float linv = 1.0f / L;

  short* AHs = (short*)&ws[WS_AH];
  short* ALs = (short*)&ws[WS_AL];
  for (int idx = tid; idx < KK * KK; idx += nt) {
    int a = idx / KK, b = idx % KK;
    float v = ws[WS_A + idx] * linv;
    float av = ((a == b) ? 1.0f : 0.0f) - v;
    short h = f2bf(av);
    AHs[idx] = h;
    ALs[idx] = f2bf(av - bf2f(h));
  }
  if (tid == 0) {
    ws[WS_LINV] = linv;
    ws[WS_LAMBD] = 0.1f * linv;
    double ts = 1.0;
    for (int k = 0; k < MAXIT; k++) {
      double tn = (1.0 + sqrt(1.0 + 4.0 * ts * ts)) * 0.5;
      ws[WS_TTS + k] = (float)((ts - 1.0) / tn);
      ts = tn;
    }
  }
}

// Block: 32 columns, 10 waves; wave w owns output rows 16w..16w+15.
// A (symmetric) held in registers as bf16 hi/lo fragments; y double-buffered
// in LDS as bf16 hi/lo, [col][k] k-contiguous, one barrier per iteration.
// mode 0: run MAXIT iters, accumulate per-iter ||dx||^2 into ws[WS_PART+it].
// mode 1: if kstar < MAXIT-1, re-run kstar+1 iters to reproduce frozen x.
__global__ __launch_bounds__(NTHR, 3)
void fista_kernel(const float* __restrict__ x, float* __restrict__ out,
                  float* __restrict__ ws, int mode) {
  __shared__ __align__(16) short ys[2][2][COLS * YS];  // [buf][hi/lo][col*YS+k]
  __shared__ float red[2][NW];

  int niter = MAXIT;
  if (mode == 1) {
    int kstar = *(const int*)&ws[WS_KSTAR];
    if (kstar >= MAXIT - 1) return;
    niter = kstar + 1;
  }

  const int tid  = threadIdx.x;
  const int w    = tid >> 6;
  const int lane = tid & 63;
  const int quad = lane >> 4;
  const int l16  = lane & 15;
  const int bid  = blockIdx.x;
  const int c0   = bid * COLS;
  const int bb   = c0 / PP;
  const int p0   = c0 % PP;
  const float linv  = ws[WS_LINV];
  const float lambd = ws[WS_LAMBD];
  const int r0 = 16 * w + 4 * quad;   // C-layout row base for this lane

  // ---- prologue: stage D + x slice into LDS (aliased over ys) ----
  float* Dl  = (float*)&ys[0][0][0];     // 5760 floats
  float* xsl = Dl + TT * KK;             // 1152 floats
  for (int idx = tid; idx < TT * KK; idx += NTHR) Dl[idx] = ws[WS_D + idx];
  for (int idx = tid; idx < TT * COLS; idx += NTHR) {
    int t = idx >> 5, c = idx & 31;
    xsl[idx] = x[((size_t)bb * TT + t) * PP + p0 + c];
  }
  __syncthreads();

  // A fragments (registers for the whole kernel): row = 16w + l16
  const short* AH = (const short*)&ws[WS_AH];
  const short* AL = (const short*)&ws[WS_AL];
  shortx8 ah[5], al[5];
  const int rowA = 16 * w + l16;
#pragma unroll
  for (int kc = 0; kc < 5; kc++) {
    int off = rowA * KK + 32 * kc + 8 * quad;
    ah[kc] = *(const shortx8*)&AH[off];
    al[kc] = *(const shortx8*)&AL[off];
  }

  // dty (scaled by linv) in C-layout: rows r0..r0+3, cols {l16, 16+l16}
  float dty[2][4] = {{0.f,0.f,0.f,0.f},{0.f,0.f,0.f,0.f}};
  for (int t = 0; t < TT; t++) {
    float4 d4 = *(const float4*)&Dl[t * KK + r0];
    float xv0 = xsl[t * COLS + l16];
    float xv1 = xsl[t * COLS + 16 + l16];
    dty[0][0] = fmaf(d4.x, xv0, dty[0][0]);
    dty[0][1] = fmaf(d4.y, xv0, dty[0][1]);
    dty[0][2] = fmaf(d4.z, xv0, dty[0][2]);
    dty[0][3] = fmaf(d4.w, xv0, dty[0][3]);
    dty[1][0] = fmaf(d4.x, xv1, dty[1][0]);
    dty[1][1] = fmaf(d4.y, xv1, dty[1][1]);
    dty[1][2] = fmaf(d4.z, xv1, dty[1][2]);
    dty[1][3] = fmaf(d4.w, xv1, dty[1][3]);
  }
#pragma unroll
  for (int ct = 0; ct < 2; ct++)
#pragma unroll
    for (int r = 0; r < 4; r++) dty[ct][r] *= linv;
  __syncthreads();

  // zero buffer 0 (y = 0); buffer 1 is fully overwritten before first read
  int* z = (int*)&ys[0][0][0];
  for (int idx = tid; idx < COLS * YS; idx += NTHR) z[idx] = 0;
  __syncthreads();

  float xo[2][4] = {{0.f,0.f,0.f,0.f},{0.f,0.f,0.f,0.f}};
  int buf = 0;
  for (int it = 0; it < niter; it++) {
    floatx4 accA[2] = {{0.f,0.f,0.f,0.f},{0.f,0.f,0.f,0.f}};
    floatx4 accB[2] = {{0.f,0.f,0.f,0.f},{0.f,0.f,0.f,0.f}};
    const short* yh = &ys[buf][0][0];
    const short* yl = &ys[buf][1][0];
#pragma unroll
    for (int ct = 0; ct < 2; ct++) {
      const int cb = (16 * ct + l16) * YS + 8 * quad;
#pragma unroll
      for (int kc = 0; kc < 5; kc++) {
        shortx8 bh = *(const shortx8*)&yh[cb + 32 * kc];
        shortx8 bl = *(const shortx8*)&yl[cb + 32 * kc];
        accA[ct] = __builtin_amdgcn_mfma_f32_16x16x32_bf16(ah[kc], bh, accA[ct], 0, 0, 0);
        accB[ct] = __builtin_amdgcn_mfma_f32_16x16x32_bf16(ah[kc], bl, accB[ct], 0, 0, 0);
        accB[ct] = __builtin_amdgcn_mfma_f32_16x16x32_bf16(al[kc], bh, accB[ct], 0, 0, 0);
      }
    }

    const float tt = ws[WS_TTS + it];
    const int nb = buf ^ 1;
    float lsum = 0.f;
#pragma unroll
    for (int ct = 0; ct < 2; ct++) {
      shortx4 hv, lv;
#pragma unroll
      for (int r = 0; r < 4; r++) {
        float v  = accA[ct][r] + accB[ct][r] + dty[ct][r];
        float aa = fabsf(v) - lambd;
        float xv = (aa > 0.f) ? ((v < 0.f) ? -aa : aa) : 0.f;
        float dd = xv - xo[ct][r];
        lsum = fmaf(dd, dd, lsum);
        float yn = fmaf(tt, dd, xv);
        xo[ct][r] = xv;
        short h = f2bf(yn);
        hv[r] = h;
        lv[r] = f2bf(yn - bf2f(h));
      }
      const int ko = (16 * ct + l16) * YS + r0;  // 4 consecutive k = rows
      *(shortx4*)&ys[nb][0][ko] = hv;
      *(shortx4*)&ys[nb][1][ko] = lv;
    }

    if (mode == 0) {
#pragma unroll
      for (int off = 32; off > 0; off >>= 1) lsum += __shfl_down(lsum, off, 64);
      if (lane == 0) red[it & 1][w] = lsum;
    }
    __syncthreads();   // writes to buf^1 + red visible; all reads of buf done
    if (mode == 0 && tid == 0) {
      float s = 0.f;
#pragma unroll
      for (int i = 0; i < NW; i++) s += red[it & 1][i];
      atomicAdd(&ws[WS_PART + it], s);
    }
    buf = nb;
  }

#pragma unroll
  for (int ct = 0; ct < 2; ct++)
#pragma unroll
    for (int r = 0; r < 4; r++)
      out[((size_t)bb * KK + r0 + r) * PP + p0 + 16 * ct + l16] = xo[ct][r];
}

__global__ void conv_scan(float* __restrict__ ws) {
  __shared__ unsigned char conv[MAXIT];
  const int tid = threadIdx.x;
  if (tid < MAXIT) {
    float s = ws[WS_PART + tid];
    float denom = (tid == 0) ? 4096.0f : 160.0f;
    conv[tid] = (sqrtf(s) / denom < 1e-4f) ? 1 : 0;
  }
  __syncthreads();
  if (tid == 0) {
    int kstar = MAXIT;
    for (int it = 0; it < MAXIT; it++)
      if (conv[it]) { kstar = it; break; }
    *reinterpret_cast<int*>(&ws[WS_KSTAR]) = kstar;
  }
}

extern "C" void kernel_launch(void* const* d_in, const int* in_sizes, int n_in,
                              void* d_out, int out_size, void* d_ws, size_t ws_size,
                              hipStream_t stream) {
  const float* Drr = (const float*)d_in[0];
  const float* Dth = (const float*)d_in[1];
  const float* x   = (const float*)d_in[2];
  float* out = (float*)d_out;
  float* ws  = (float*)d_ws;

  setup_kernel<<<1, 1024, 0, stream>>>(Drr, Dth, ws);
  fista_kernel<<<256, NTHR, 0, stream>>>(x, out, ws, 0);
  conv_scan<<<1, 128, 0, stream>>>(ws);
  fista_kernel<<<256, NTHR, 0, stream>>>(x, out, ws, 1);
}